// Round 5
// baseline (100.528 us; speedup 1.0000x reference)
//
#include <hip/hip_runtime.h>

#define BN_EPS 1e-5f

constexpr int Bb = 2;
constexpr int Cc = 64;
constexpr int Nn = 32768;
constexpr int Kk = 16;
constexpr int Oo = 64;

typedef __attribute__((ext_vector_type(8))) short v8s;   // 8 x bf16 (4 VGPRs)
typedef __attribute__((ext_vector_type(4))) float v4f;   // MFMA C/D

__device__ __forceinline__ unsigned short f2bf(float f) {
    unsigned u = __float_as_uint(f);
    return (unsigned short)((u + 0x7FFFu + ((u >> 16) & 1u)) >> 16);  // RNE
}

// Kernel 1: LDS-free MFMA gemm. A = W (m=o), B = feature (j=n) so that
// D row = o: each lane holds 4 CONSECUTIVE o per tile -> ushort4 stores.
// t[b][n][o] = bf16(relu(inv[o]*(W[o,:].f[:,n]) + bias[o])), o-contiguous.
// b = blk&1: round-robin blk->XCD puts one batch per XCD group (L2 locality).
__global__ __launch_bounds__(256) void spe_gemm_mfma(
    const float* __restrict__ feature, const float* __restrict__ W,
    const float* __restrict__ gamma, const float* __restrict__ beta,
    const float* __restrict__ rmean, const float* __restrict__ rvar,
    unsigned short* __restrict__ t)
{
    const int tid = threadIdx.x;
    const int blk = blockIdx.x;             // 1024 = 2 batches x 512 tiles
    const int b   = blk & 1;
    const int n0  = (blk >> 1) << 6;

    const int wv   = tid >> 6;      // wave 0..3: n-rows [wv*16, wv*16+16)
    const int lane = tid & 63;
    const int q    = lane >> 4;     // quad: k-chunk q*8 within K=32
    const int r16  = lane & 15;

    union U { ushort4 u4[2]; unsigned short us[8]; v8s v; };

    // ---- B-frags (feature): B[k=c][j=n], lane j = r16 -> n, k = q*8+jj ----
    const int nb = n0 + wv * 16 + r16;          // this lane's n (D col)
    const float* fp = feature + (size_t)b * Cc * Nn + nb;
    U bf0, bf1;
    #pragma unroll
    for (int jj = 0; jj < 8; ++jj) {            // 16 coalesced-by-16-lane loads
        bf0.us[jj] = f2bf(fp[(size_t)(q * 8 + jj) * Nn]);
        bf1.us[jj] = f2bf(fp[(size_t)(q * 8 + jj + 32) * Nn]);
    }

    // ---- 4 o-tiles: A-frags from W (L1-resident), MFMA, fused epilogue ----
    #pragma unroll
    for (int ot = 0; ot < 4; ++ot) {
        const int oa = ot * 16 + r16;           // A row m = o
        const float* wp = W + oa * 64 + q * 8;
        U af0, af1;
        #pragma unroll
        for (int jj = 0; jj < 8; ++jj) {
            af0.us[jj] = f2bf(wp[jj]);
            af1.us[jj] = f2bf(wp[jj + 32]);
        }
        v4f c = {0.f, 0.f, 0.f, 0.f};
        c = __builtin_amdgcn_mfma_f32_16x16x32_bf16(af0.v, bf0.v, c, 0, 0, 0);
        c = __builtin_amdgcn_mfma_f32_16x16x32_bf16(af1.v, bf1.v, c, 0, 0, 0);

        // D[row = o = ot*16 + q*4 + r][col = n = nb]; BN+ReLU, pack ushort4
        const int ob4 = ot * 16 + q * 4;
        const float4 g4  = *(const float4*)&gamma[ob4];
        const float4 be4 = *(const float4*)&beta[ob4];
        const float4 m4  = *(const float4*)&rmean[ob4];
        const float4 v4  = *(const float4*)&rvar[ob4];
        float inv[4], bias[4];
        inv[0] = g4.x / sqrtf(v4.x + BN_EPS);  bias[0] = be4.x - m4.x * inv[0];
        inv[1] = g4.y / sqrtf(v4.y + BN_EPS);  bias[1] = be4.y - m4.y * inv[1];
        inv[2] = g4.z / sqrtf(v4.z + BN_EPS);  bias[2] = be4.z - m4.z * inv[2];
        inv[3] = g4.w / sqrtf(v4.w + BN_EPS);  bias[3] = be4.w - m4.w * inv[3];

        ushort4 ov;
        ov.x = f2bf(fmaxf(fmaf(inv[0], c[0], bias[0]), 0.0f));
        ov.y = f2bf(fmaxf(fmaf(inv[1], c[1], bias[1]), 0.0f));
        ov.z = f2bf(fmaxf(fmaf(inv[2], c[2], bias[2]), 0.0f));
        ov.w = f2bf(fmaxf(fmaf(inv[3], c[3], bias[3]), 0.0f));
        *(ushort4*)&t[((size_t)b * Nn + nb) * 64 + ob4] = ov;   // 8B store
    }
}

// Kernel 2: out[b][o][n] = t[b][n][o] + sum_j t[b][idx[b][n][j]][o]
// 8 waves/block, wave owns 8 points: lane=(p,e), p=point(0..7), e=o-octet.
// All 17 gathers (16B/lane) loaded into a live array BEFORE accumulation ->
// ~68 dest VGPRs in flight, latency hidden. launch_bounds(512,4): <=128 VGPR.
__global__ __launch_bounds__(512, 4) void spe_gather_sum(
    const unsigned short* __restrict__ t, const int* __restrict__ idx,
    float* __restrict__ out)
{
    __shared__ float s[64 * 65];      // stride 65 + scalar ops: conflict-free
    const int tid  = threadIdx.x;
    const int wv   = tid >> 6;        // 0..7
    const int lane = tid & 63;
    const int p    = lane >> 3;       // point within wave group
    const int e    = lane & 7;        // o-octet (o = e*8 .. e*8+8)
    const int blk  = blockIdx.x;
    const int b    = blk & 1;
    const int n0   = (blk >> 1) << 6;
    const int ng   = n0 + wv * 8;

    const unsigned short* tb = t + (size_t)b * Nn * 64;

    // 8 points x 16 idx = 128 ints: one coalesced int2 load (8B/lane)
    const int2 mi = ((const int2*)(idx + ((size_t)b * Nn + ng) * Kk))[lane];

    const int n = ng + p;
    uint4 v[17];
    v[0] = *(const uint4*)&tb[(size_t)n * 64 + e * 8];            // center
    #pragma unroll
    for (int j = 0; j < 16; ++j) {
        const int src = p * 8 + (j >> 1);
        const int nj  = __shfl((j & 1) ? mi.y : mi.x, src);
        v[j + 1] = *(const uint4*)&tb[(size_t)nj * 64 + e * 8];   // 16B gather
    }

    float acc[8] = {0.f, 0.f, 0.f, 0.f, 0.f, 0.f, 0.f, 0.f};
    #pragma unroll
    for (int j = 0; j < 17; ++j) {
        acc[0] += __uint_as_float(v[j].x << 16);
        acc[1] += __uint_as_float(v[j].x & 0xFFFF0000u);
        acc[2] += __uint_as_float(v[j].y << 16);
        acc[3] += __uint_as_float(v[j].y & 0xFFFF0000u);
        acc[4] += __uint_as_float(v[j].z << 16);
        acc[5] += __uint_as_float(v[j].z & 0xFFFF0000u);
        acc[6] += __uint_as_float(v[j].w << 16);
        acc[7] += __uint_as_float(v[j].w & 0xFFFF0000u);
    }

    float* sp = &s[(wv * 8 + p) * 65 + e * 8];
    #pragma unroll
    for (int i = 0; i < 8; ++i) sp[i] = acc[i];   // scalar: banks p+8e+i, 2-way max
    __syncthreads();

    // transpose write-out: lanes over n => coalesced 256B stores
    const int nl2 = tid & 63;
    const int ob  = tid >> 6;          // 0..7
    float* op = out + (size_t)b * Oo * Nn + n0 + nl2;
    #pragma unroll
    for (int i = 0; i < 8; ++i) {
        const int o = ob * 8 + i;
        op[(size_t)o * Nn] = s[nl2 * 65 + o];
    }
}

extern "C" void kernel_launch(void* const* d_in, const int* in_sizes, int n_in,
                              void* d_out, int out_size, void* d_ws, size_t ws_size,
                              hipStream_t stream) {
    const float* feature = (const float*)d_in[0];
    const int*   nidx    = (const int*)d_in[1];
    const float* W       = (const float*)d_in[2];
    const float* gamma   = (const float*)d_in[3];
    const float* beta    = (const float*)d_in[4];
    const float* rmean   = (const float*)d_in[5];
    const float* rvar    = (const float*)d_in[6];
    float* out = (float*)d_out;
    unsigned short* t = (unsigned short*)d_ws;   // B*N*O*2 = 8 MiB bf16

    const int nblocks = Bb * (Nn / 64);  // 1024
    spe_gemm_mfma<<<nblocks, 256, 0, stream>>>(feature, W, gamma, beta, rmean, rvar, t);
    spe_gather_sum<<<nblocks, 512, 0, stream>>>(t, nidx, out);
}

// Round 6
// 95.252 us; speedup vs baseline: 1.0554x; 1.0554x over previous
//
#include <hip/hip_runtime.h>

#define BN_EPS 1e-5f

constexpr int Bb = 2;
constexpr int Cc = 64;
constexpr int Nn = 32768;
constexpr int Kk = 16;
constexpr int Oo = 64;

typedef __attribute__((ext_vector_type(8))) short v8s;   // 8 x bf16 (4 VGPRs)
typedef __attribute__((ext_vector_type(4))) float v4f;   // MFMA C/D

__device__ __forceinline__ unsigned short f2bf(float f) {
    unsigned u = __float_as_uint(f);
    return (unsigned short)((u + 0x7FFFu + ((u >> 16) & 1u)) >> 16);  // RNE
}
__device__ __forceinline__ float bf2f(unsigned short h) {
    return __uint_as_float(((unsigned)h) << 16);
}

// Kernel 1: MFMA gemm, A = W (m=o), B = feature (j=n) -> D row = o, so each
// lane holds 4 consecutive o per tile -> ushort4 epilogue stores (R5 mapping,
// pass-verified). W staged via LDS with coalesced reads (fixes R5's 1024
// L1-transactions/wave W-load storm). Feature B-frags direct from global
// (4 x 64B segments per instr, no overfetch). One barrier.
// b = blk&1: round-robin blk->XCD gives one batch per XCD parity (L2 locality).
__global__ __launch_bounds__(256) void spe_gemm_mfma(
    const float* __restrict__ feature, const float* __restrict__ W,
    const float* __restrict__ gamma, const float* __restrict__ beta,
    const float* __restrict__ rmean, const float* __restrict__ rvar,
    unsigned short* __restrict__ t)
{
    __shared__ unsigned short Wl[64][68];   // Wl[o][c], +4 pad -> 4-way max on frag reads
    const int tid = threadIdx.x;
    const int blk = blockIdx.x;             // 1024 = 2 batches x 512 tiles
    const int b   = blk & 1;
    const int n0  = (blk >> 1) << 6;

    // stage W: wave j writes rows 4j.. (global coalesced, LDS 2-way max)
    #pragma unroll
    for (int j = 0; j < 16; ++j) {
        const int i = j * 256 + tid;        // consecutive within wave
        Wl[i >> 6][i & 63] = f2bf(W[i]);
    }

    const int wv   = tid >> 6;      // wave: n-rows [wv*16, wv*16+16)
    const int lane = tid & 63;
    const int q    = lane >> 4;     // k-chunk q*8 within K=32
    const int r16  = lane & 15;

    union U { ushort4 u4[2]; unsigned short us[8]; v8s v; };

    // B-frags (feature) from global: lane j=r16 -> n, k = q*8+jj (+0 / +32)
    const int nb = n0 + wv * 16 + r16;
    const float* fp = feature + (size_t)b * Cc * Nn + nb;
    U bf0, bf1;
    #pragma unroll
    for (int jj = 0; jj < 8; ++jj) {
        bf0.us[jj] = f2bf(fp[(size_t)(q * 8 + jj) * Nn]);
        bf1.us[jj] = f2bf(fp[(size_t)(q * 8 + jj + 32) * Nn]);
    }
    __syncthreads();

    #pragma unroll
    for (int ot = 0; ot < 4; ++ot) {
        const int oa = ot * 16 + r16;       // A row m = o
        U af0, af1;
        af0.u4[0] = *(const ushort4*)&Wl[oa][q * 8];
        af0.u4[1] = *(const ushort4*)&Wl[oa][q * 8 + 4];
        af1.u4[0] = *(const ushort4*)&Wl[oa][q * 8 + 32];
        af1.u4[1] = *(const ushort4*)&Wl[oa][q * 8 + 36];

        v4f c = {0.f, 0.f, 0.f, 0.f};
        c = __builtin_amdgcn_mfma_f32_16x16x32_bf16(af0.v, bf0.v, c, 0, 0, 0);
        c = __builtin_amdgcn_mfma_f32_16x16x32_bf16(af1.v, bf1.v, c, 0, 0, 0);

        // D[row = o = ot*16 + q*4 + r][col = n = nb]; BN+ReLU, ushort4 store
        const int ob4 = ot * 16 + q * 4;
        const float4 g4  = *(const float4*)&gamma[ob4];
        const float4 be4 = *(const float4*)&beta[ob4];
        const float4 m4  = *(const float4*)&rmean[ob4];
        const float4 v4  = *(const float4*)&rvar[ob4];
        float inv[4], bias[4];
        inv[0] = g4.x / sqrtf(v4.x + BN_EPS);  bias[0] = be4.x - m4.x * inv[0];
        inv[1] = g4.y / sqrtf(v4.y + BN_EPS);  bias[1] = be4.y - m4.y * inv[1];
        inv[2] = g4.z / sqrtf(v4.z + BN_EPS);  bias[2] = be4.z - m4.z * inv[2];
        inv[3] = g4.w / sqrtf(v4.w + BN_EPS);  bias[3] = be4.w - m4.w * inv[3];

        ushort4 ov;
        ov.x = f2bf(fmaxf(fmaf(inv[0], c[0], bias[0]), 0.0f));
        ov.y = f2bf(fmaxf(fmaf(inv[1], c[1], bias[1]), 0.0f));
        ov.z = f2bf(fmaxf(fmaf(inv[2], c[2], bias[2]), 0.0f));
        ov.w = f2bf(fmaxf(fmaf(inv[3], c[3], bias[3]), 0.0f));
        *(ushort4*)&t[((size_t)b * Nn + nb) * 64 + ob4] = ov;
    }
}

// Kernel 2: out[b][o][n] = t[b][n][o] + sum_j t[b][idx[b][n][j]][o]
// R4 shape (1024 thr, 4 pts/wave, 8B ushort4 gathers) but with explicit
// three-phase hoist: shfl all 16 indices -> issue ALL 17 loads -> accumulate.
// ~34 data + ~17 offset VGPRs << 128 cap; 17 loads in flight hides L2 latency.
__global__ __launch_bounds__(1024, 4) void spe_gather_sum(
    const unsigned short* __restrict__ t, const int* __restrict__ idx,
    float* __restrict__ out)
{
    __shared__ float s[64 * 65];      // stride 65 -> conflict-free transpose
    const int tid  = threadIdx.x;
    const int wv   = tid >> 6;        // 0..15
    const int lane = tid & 63;
    const int p    = lane >> 4;       // point 0..3
    const int q    = lane & 15;       // o-quad (o = q*4 .. q*4+4)
    const int blk  = blockIdx.x;
    const int b    = blk & 1;
    const int n0   = (blk >> 1) << 6;
    const int ng   = n0 + wv * 4;

    const unsigned short* tb = t + (size_t)b * Nn * 64;

    const int myidx = idx[((size_t)b * Nn + ng) * Kk + lane];  // 256B coalesced

    // phase 1: all neighbor indices via shfl
    int nj[16];
    #pragma unroll
    for (int j = 0; j < 16; ++j) nj[j] = __shfl(myidx, p * 16 + j);

    // phase 2: all 17 gathers issued back-to-back (independent)
    ushort4 v[17];
    v[0] = *(const ushort4*)&tb[(size_t)(ng + p) * 64 + q * 4];
    #pragma unroll
    for (int j = 0; j < 16; ++j)
        v[j + 1] = *(const ushort4*)&tb[(size_t)nj[j] * 64 + q * 4];

    // phase 3: fp32 accumulate
    float ax = 0.f, ay = 0.f, az = 0.f, aw = 0.f;
    #pragma unroll
    for (int j = 0; j < 17; ++j) {
        ax += bf2f(v[j].x); ay += bf2f(v[j].y);
        az += bf2f(v[j].z); aw += bf2f(v[j].w);
    }

    float* sp = &s[(wv * 4 + p) * 65 + q * 4];
    sp[0] = ax; sp[1] = ay; sp[2] = az; sp[3] = aw;
    __syncthreads();

    // transpose write-out: lanes over n => coalesced 256B stores
    const int nl2 = tid & 63;
    const int ob  = tid >> 6;          // 0..15
    float* op = out + (size_t)b * Oo * Nn + n0 + nl2;
    #pragma unroll
    for (int i = 0; i < 4; ++i) {
        const int o = ob * 4 + i;
        op[(size_t)o * Nn] = s[nl2 * 65 + o];
    }
}

extern "C" void kernel_launch(void* const* d_in, const int* in_sizes, int n_in,
                              void* d_out, int out_size, void* d_ws, size_t ws_size,
                              hipStream_t stream) {
    const float* feature = (const float*)d_in[0];
    const int*   nidx    = (const int*)d_in[1];
    const float* W       = (const float*)d_in[2];
    const float* gamma   = (const float*)d_in[3];
    const float* beta    = (const float*)d_in[4];
    const float* rmean   = (const float*)d_in[5];
    const float* rvar    = (const float*)d_in[6];
    float* out = (float*)d_out;
    unsigned short* t = (unsigned short*)d_ws;   // B*N*O*2 = 8 MiB bf16

    const int nblocks = Bb * (Nn / 64);  // 1024
    spe_gemm_mfma<<<nblocks, 256, 0, stream>>>(feature, W, gamma, beta, rmean, rvar, t);
    spe_gather_sum<<<nblocks, 1024, 0, stream>>>(t, nidx, out);
}

// Round 7
// 94.145 us; speedup vs baseline: 1.0678x; 1.0118x over previous
//
#include <hip/hip_runtime.h>

#define BN_EPS 1e-5f

constexpr int Bb = 2;
constexpr int Cc = 64;
constexpr int Nn = 32768;
constexpr int Kk = 16;
constexpr int Oo = 64;

typedef __attribute__((ext_vector_type(8))) short v8s;   // 8 x bf16 (4 VGPRs)
typedef __attribute__((ext_vector_type(4))) float v4f;   // MFMA C/D

__device__ __forceinline__ unsigned short f2bf(float f) {
    unsigned u = __float_as_uint(f);
    return (unsigned short)((u + 0x7FFFu + ((u >> 16) & 1u)) >> 16);  // RNE
}

// Kernel 1: MFMA gemm, A = W (m=o), B = feature (j=n) -> D row = o, each lane
// holds 4 consecutive o per tile -> ushort4 epilogue stores. W staged via LDS
// (coalesced); feature B-frags direct from global (4 x 64B segs/instr).
// BN inv/bias precomputed once per block into LDS (kills 16 sqrt+rcp/thread).
// b = blk&1: round-robin blk->XCD gives one batch per XCD parity.
__global__ __launch_bounds__(256) void spe_gemm_mfma(
    const float* __restrict__ feature, const float* __restrict__ W,
    const float* __restrict__ gamma, const float* __restrict__ beta,
    const float* __restrict__ rmean, const float* __restrict__ rvar,
    unsigned short* __restrict__ t)
{
    __shared__ unsigned short Wl[64][68];   // Wl[o][c], +4 pad
    __shared__ float invs[64], biass[64];
    const int tid = threadIdx.x;
    const int blk = blockIdx.x;             // 1024 = 2 batches x 512 tiles
    const int b   = blk & 1;
    const int n0  = (blk >> 1) << 6;

    // stage W (coalesced) + BN precompute (one sqrt/rcp per o, threads 0-63)
    #pragma unroll
    for (int j = 0; j < 16; ++j) {
        const int i = j * 256 + tid;
        Wl[i >> 6][i & 63] = f2bf(W[i]);
    }
    if (tid < 64) {
        const float iv = gamma[tid] / sqrtf(rvar[tid] + BN_EPS);
        invs[tid]  = iv;
        biass[tid] = beta[tid] - rmean[tid] * iv;
    }

    const int wv   = tid >> 6;      // wave: n-rows [wv*16, wv*16+16)
    const int lane = tid & 63;
    const int q    = lane >> 4;     // k-chunk q*8 within K=32
    const int r16  = lane & 15;

    union U { ushort4 u4[2]; unsigned short us[8]; v8s v; };

    // B-frags (feature) from global: lane j=r16 -> n, k = q*8+jj (+0 / +32)
    const int nb = n0 + wv * 16 + r16;
    const float* fp = feature + (size_t)b * Cc * Nn + nb;
    U bf0, bf1;
    #pragma unroll
    for (int jj = 0; jj < 8; ++jj) {
        bf0.us[jj] = f2bf(fp[(size_t)(q * 8 + jj) * Nn]);
        bf1.us[jj] = f2bf(fp[(size_t)(q * 8 + jj + 32) * Nn]);
    }
    __syncthreads();

    #pragma unroll
    for (int ot = 0; ot < 4; ++ot) {
        const int oa = ot * 16 + r16;       // A row m = o
        U af0, af1;
        af0.u4[0] = *(const ushort4*)&Wl[oa][q * 8];
        af0.u4[1] = *(const ushort4*)&Wl[oa][q * 8 + 4];
        af1.u4[0] = *(const ushort4*)&Wl[oa][q * 8 + 32];
        af1.u4[1] = *(const ushort4*)&Wl[oa][q * 8 + 36];

        v4f c = {0.f, 0.f, 0.f, 0.f};
        c = __builtin_amdgcn_mfma_f32_16x16x32_bf16(af0.v, bf0.v, c, 0, 0, 0);
        c = __builtin_amdgcn_mfma_f32_16x16x32_bf16(af1.v, bf1.v, c, 0, 0, 0);

        // D[row = o = ot*16 + q*4 + r][col = n = nb]; BN+ReLU, ushort4 store
        const int ob4 = ot * 16 + q * 4;
        const float4 iv4 = *(const float4*)&invs[ob4];
        const float4 bi4 = *(const float4*)&biass[ob4];

        ushort4 ov;
        ov.x = f2bf(fmaxf(fmaf(iv4.x, c[0], bi4.x), 0.0f));
        ov.y = f2bf(fmaxf(fmaf(iv4.y, c[1], bi4.y), 0.0f));
        ov.z = f2bf(fmaxf(fmaf(iv4.z, c[2], bi4.z), 0.0f));
        ov.w = f2bf(fmaxf(fmaf(iv4.w, c[3], bi4.w), 0.0f));
        *(ushort4*)&t[((size_t)b * Nn + nb) * 64 + ob4] = ov;
    }
}

// Kernel 2: out[b][o][n] = t[b][n][o] + sum_j t[b][idx[b][n][j]][o]
// 8 waves/block (512 thr), wave owns 8 points: lane=(p,e), p=point 0..7,
// e=o-octet. 17 x 16B gathers per lane, ALL issued before accumulation
// (~68 dest VGPRs in flight). launch_bounds(512,2): VGPR cap 256 -> no
// serialization (R5's (512,4)=128-cap bug fixed).
__global__ __launch_bounds__(512, 2) void spe_gather_sum(
    const unsigned short* __restrict__ t, const int* __restrict__ idx,
    float* __restrict__ out)
{
    __shared__ float s[64 * 65];      // stride 65: 2-way max both phases (free)
    const int tid  = threadIdx.x;
    const int wv   = tid >> 6;        // 0..7
    const int lane = tid & 63;
    const int p    = lane >> 3;       // point 0..7
    const int e    = lane & 7;        // o-octet (o = e*8 .. e*8+8)
    const int blk  = blockIdx.x;
    const int b    = blk & 1;
    const int n0   = (blk >> 1) << 6;
    const int ng   = n0 + wv * 8;

    const unsigned short* tb = t + (size_t)b * Nn * 64;

    // 8 points x 16 idx = 128 ints: int2/lane, coalesced 512B
    const int2 mi = ((const int2*)(idx + ((size_t)b * Nn + ng) * Kk))[lane];

    // phase 1: all neighbor indices via shfl
    // tap j of point p lives in lane p*8 + (j>>1), component (j&1)
    int nj[16];
    #pragma unroll
    for (int j = 0; j < 16; ++j)
        nj[j] = __shfl((j & 1) ? mi.y : mi.x, p * 8 + (j >> 1));

    // phase 2: all 17 gathers issued back-to-back (16B each, independent)
    uint4 v[17];
    v[0] = *(const uint4*)&tb[(size_t)(ng + p) * 64 + e * 8];
    #pragma unroll
    for (int j = 0; j < 16; ++j)
        v[j + 1] = *(const uint4*)&tb[(size_t)nj[j] * 64 + e * 8];

    // phase 3: fp32 accumulate (unpack bf16 pairs: 1 shl / 1 and each)
    float acc[8] = {0.f, 0.f, 0.f, 0.f, 0.f, 0.f, 0.f, 0.f};
    #pragma unroll
    for (int j = 0; j < 17; ++j) {
        acc[0] += __uint_as_float(v[j].x << 16);
        acc[1] += __uint_as_float(v[j].x & 0xFFFF0000u);
        acc[2] += __uint_as_float(v[j].y << 16);
        acc[3] += __uint_as_float(v[j].y & 0xFFFF0000u);
        acc[4] += __uint_as_float(v[j].z << 16);
        acc[5] += __uint_as_float(v[j].z & 0xFFFF0000u);
        acc[6] += __uint_as_float(v[j].w << 16);
        acc[7] += __uint_as_float(v[j].w & 0xFFFF0000u);
    }

    float* sp = &s[(wv * 8 + p) * 65 + e * 8];
    #pragma unroll
    for (int i = 0; i < 8; ++i) sp[i] = acc[i];   // banks (p+8e+i)%32: 2-way
    __syncthreads();

    // transpose write-out: lanes over n => coalesced 256B stores
    const int nl2 = tid & 63;
    const int ob  = tid >> 6;          // 0..7
    float* op = out + (size_t)b * Oo * Nn + n0 + nl2;
    #pragma unroll
    for (int i = 0; i < 8; ++i) {
        const int o = ob * 8 + i;
        op[(size_t)o * Nn] = s[nl2 * 65 + o];
    }
}

extern "C" void kernel_launch(void* const* d_in, const int* in_sizes, int n_in,
                              void* d_out, int out_size, void* d_ws, size_t ws_size,
                              hipStream_t stream) {
    const float* feature = (const float*)d_in[0];
    const int*   nidx    = (const int*)d_in[1];
    const float* W       = (const float*)d_in[2];
    const float* gamma   = (const float*)d_in[3];
    const float* beta    = (const float*)d_in[4];
    const float* rmean   = (const float*)d_in[5];
    const float* rvar    = (const float*)d_in[6];
    float* out = (float*)d_out;
    unsigned short* t = (unsigned short*)d_ws;   // B*N*O*2 = 8 MiB bf16

    const int nblocks = Bb * (Nn / 64);  // 1024
    spe_gemm_mfma<<<nblocks, 256, 0, stream>>>(feature, W, gamma, beta, rmean, rvar, t);
    spe_gather_sum<<<nblocks, 512, 0, stream>>>(t, nidx, out);
}

// Round 8
// 93.733 us; speedup vs baseline: 1.0725x; 1.0044x over previous
//
#include <hip/hip_runtime.h>

#define BN_EPS 1e-5f

constexpr int Bb = 2;
constexpr int Cc = 64;
constexpr int Nn = 32768;
constexpr int Kk = 16;
constexpr int Oo = 64;

typedef __attribute__((ext_vector_type(8))) short v8s;   // 8 x bf16 (4 VGPRs)
typedef __attribute__((ext_vector_type(4))) float v4f;   // MFMA C/D

__device__ __forceinline__ unsigned short f2bf(float f) {
    unsigned u = __float_as_uint(f);
    return (unsigned short)((u + 0x7FFFu + ((u >> 16) & 1u)) >> 16);  // RNE
}

// Kernel 1: MFMA gemm, A = W (m=o), B = feature (j=n) -> D row = o, each lane
// holds 4 consecutive o per tile -> ushort4 epilogue stores.
// R8: 256-n tile per block (256 blocks x 1024 thr): W staged ONCE per 256 n
// (4 loads/thread vs 16), 4x fewer blocks. 16 waves each own one 16-n strip.
// b = blk&1: round-robin blk->XCD gives one batch per XCD parity.
__global__ __launch_bounds__(1024) void spe_gemm_mfma(
    const float* __restrict__ feature, const float* __restrict__ W,
    const float* __restrict__ gamma, const float* __restrict__ beta,
    const float* __restrict__ rmean, const float* __restrict__ rvar,
    unsigned short* __restrict__ t)
{
    __shared__ unsigned short Wl[64][68];   // Wl[o][c], +4 pad
    __shared__ float invs[64], biass[64];
    const int tid = threadIdx.x;
    const int blk = blockIdx.x;             // 256 = 2 batches x 128 tiles
    const int b   = blk & 1;
    const int n0  = (blk >> 1) << 8;        // 256-n tile

    // stage W (coalesced, 4 rounds) + BN precompute (threads 0-63)
    #pragma unroll
    for (int j = 0; j < 4; ++j) {
        const int i = j * 1024 + tid;
        Wl[i >> 6][i & 63] = f2bf(W[i]);
    }
    if (tid < 64) {
        const float iv = gamma[tid] / sqrtf(rvar[tid] + BN_EPS);
        invs[tid]  = iv;
        biass[tid] = beta[tid] - rmean[tid] * iv;
    }

    const int wv   = tid >> 6;      // wave 0..15: n-rows [wv*16, wv*16+16)
    const int lane = tid & 63;
    const int q    = lane >> 4;     // k-chunk q*8 within K=32
    const int r16  = lane & 15;

    union U { ushort4 u4[2]; unsigned short us[8]; v8s v; };

    // B-frags (feature) from global: lane j=r16 -> n, k = q*8+jj (+0 / +32)
    const int nb = n0 + wv * 16 + r16;
    const float* fp = feature + (size_t)b * Cc * Nn + nb;
    U bf0, bf1;
    #pragma unroll
    for (int jj = 0; jj < 8; ++jj) {
        bf0.us[jj] = f2bf(fp[(size_t)(q * 8 + jj) * Nn]);
        bf1.us[jj] = f2bf(fp[(size_t)(q * 8 + jj + 32) * Nn]);
    }
    __syncthreads();

    #pragma unroll
    for (int ot = 0; ot < 4; ++ot) {
        const int oa = ot * 16 + r16;       // A row m = o
        U af0, af1;
        af0.u4[0] = *(const ushort4*)&Wl[oa][q * 8];
        af0.u4[1] = *(const ushort4*)&Wl[oa][q * 8 + 4];
        af1.u4[0] = *(const ushort4*)&Wl[oa][q * 8 + 32];
        af1.u4[1] = *(const ushort4*)&Wl[oa][q * 8 + 36];

        v4f c = {0.f, 0.f, 0.f, 0.f};
        c = __builtin_amdgcn_mfma_f32_16x16x32_bf16(af0.v, bf0.v, c, 0, 0, 0);
        c = __builtin_amdgcn_mfma_f32_16x16x32_bf16(af1.v, bf1.v, c, 0, 0, 0);

        // D[row = o = ot*16 + q*4 + r][col = n = nb]; BN+ReLU, ushort4 store
        const int ob4 = ot * 16 + q * 4;
        const float4 iv4 = *(const float4*)&invs[ob4];
        const float4 bi4 = *(const float4*)&biass[ob4];

        ushort4 ov;
        ov.x = f2bf(fmaxf(fmaf(iv4.x, c[0], bi4.x), 0.0f));
        ov.y = f2bf(fmaxf(fmaf(iv4.y, c[1], bi4.y), 0.0f));
        ov.z = f2bf(fmaxf(fmaf(iv4.z, c[2], bi4.z), 0.0f));
        ov.w = f2bf(fmaxf(fmaf(iv4.w, c[3], bi4.w), 0.0f));
        *(ushort4*)&t[((size_t)b * Nn + nb) * 64 + ob4] = ov;
    }
}

// Kernel 2: out[b][o][n] = t[b][n][o] + sum_j t[b][idx[b][n][j]][o]
// 8 waves/block (512 thr), wave owns 8 points: lane=(p,e), p=point 0..7,
// e=o-octet. 17 x 16B gathers per lane, ALL issued before accumulation
// (~68 dest VGPRs in flight). launch_bounds(512,2): VGPR cap 256.
__global__ __launch_bounds__(512, 2) void spe_gather_sum(
    const unsigned short* __restrict__ t, const int* __restrict__ idx,
    float* __restrict__ out)
{
    __shared__ float s[64 * 65];      // stride 65: 2-way max both phases (free)
    const int tid  = threadIdx.x;
    const int wv   = tid >> 6;        // 0..7
    const int lane = tid & 63;
    const int p    = lane >> 3;       // point 0..7
    const int e    = lane & 7;        // o-octet (o = e*8 .. e*8+8)
    const int blk  = blockIdx.x;
    const int b    = blk & 1;
    const int n0   = (blk >> 1) << 6;
    const int ng   = n0 + wv * 8;

    const unsigned short* tb = t + (size_t)b * Nn * 64;

    // 8 points x 16 idx = 128 ints: int2/lane, coalesced 512B
    const int2 mi = ((const int2*)(idx + ((size_t)b * Nn + ng) * Kk))[lane];

    // phase 1: all neighbor indices via shfl
    int nj[16];
    #pragma unroll
    for (int j = 0; j < 16; ++j)
        nj[j] = __shfl((j & 1) ? mi.y : mi.x, p * 8 + (j >> 1));

    // phase 2: all 17 gathers issued back-to-back (16B each, independent)
    uint4 v[17];
    v[0] = *(const uint4*)&tb[(size_t)(ng + p) * 64 + e * 8];
    #pragma unroll
    for (int j = 0; j < 16; ++j)
        v[j + 1] = *(const uint4*)&tb[(size_t)nj[j] * 64 + e * 8];

    // phase 3: fp32 accumulate (unpack bf16 pairs: 1 shl / 1 and each)
    float acc[8] = {0.f, 0.f, 0.f, 0.f, 0.f, 0.f, 0.f, 0.f};
    #pragma unroll
    for (int j = 0; j < 17; ++j) {
        acc[0] += __uint_as_float(v[j].x << 16);
        acc[1] += __uint_as_float(v[j].x & 0xFFFF0000u);
        acc[2] += __uint_as_float(v[j].y << 16);
        acc[3] += __uint_as_float(v[j].y & 0xFFFF0000u);
        acc[4] += __uint_as_float(v[j].z << 16);
        acc[5] += __uint_as_float(v[j].z & 0xFFFF0000u);
        acc[6] += __uint_as_float(v[j].w << 16);
        acc[7] += __uint_as_float(v[j].w & 0xFFFF0000u);
    }

    float* sp = &s[(wv * 8 + p) * 65 + e * 8];
    #pragma unroll
    for (int i = 0; i < 8; ++i) sp[i] = acc[i];   // banks (p+8e+i)%32: 2-way
    __syncthreads();

    // transpose write-out: lanes over n => coalesced 256B stores
    const int nl2 = tid & 63;
    const int ob  = tid >> 6;          // 0..7
    float* op = out + (size_t)b * Oo * Nn + n0 + nl2;
    #pragma unroll
    for (int i = 0; i < 8; ++i) {
        const int o = ob * 8 + i;
        op[(size_t)o * Nn] = s[nl2 * 65 + o];
    }
}

extern "C" void kernel_launch(void* const* d_in, const int* in_sizes, int n_in,
                              void* d_out, int out_size, void* d_ws, size_t ws_size,
                              hipStream_t stream) {
    const float* feature = (const float*)d_in[0];
    const int*   nidx    = (const int*)d_in[1];
    const float* W       = (const float*)d_in[2];
    const float* gamma   = (const float*)d_in[3];
    const float* beta    = (const float*)d_in[4];
    const float* rmean   = (const float*)d_in[5];
    const float* rvar    = (const float*)d_in[6];
    float* out = (float*)d_out;
    unsigned short* t = (unsigned short*)d_ws;   // B*N*O*2 = 8 MiB bf16

    spe_gemm_mfma<<<Bb * (Nn / 256), 1024, 0, stream>>>(feature, W, gamma, beta, rmean, rvar, t);
    spe_gather_sum<<<Bb * (Nn / 64), 512, 0, stream>>>(t, nidx, out);
}